// Round 3
// baseline (19293.195 us; speedup 1.0000x reference)
//
#include <hip/hip_runtime.h>
#include <hip/hip_bf16.h>

// LSTM encoder: B=64, T=2048, D=256, H=512.
// Persistent-RNN: 128 wgs (1/CU via ~150KB LDS), each owns a [768 x 64] bf16
// slice of [U;W] in LDS. Tagged-u64 dataflow sync (round-2 scheme) plus:
//  - ONE barrier per step (A). Barrier B + gt LDS bounce replaced by an
//    in-wave gate gather: wave w owns h-cols [s*16+w*4, +4) x 4 gates; after
//    per-lane activation, 3x shfl_xor(4/8/12) delivers i,f,g,o to the gi==0
//    lanes which run the pointwise (4x redundant-free). zh double-buffered
//    (required once B is gone).
//  - vmcnt discipline: per step issue order is [xr x-loads] ... [hv polls]
//    [publish stores]. First tag-check waits vmcnt(8): retires hv AND xr
//    (in-order), leaves own stores in flight -> no own-ack stall, and zx
//    staging needs no wait. Own h-slice is never polled (local LDS write
//    at publish time), so polls never depend on our own stores.
//  - x staged with v_cvt_pk_bf16_f32 (2 floats/op vs 4-op manual RTNE).
//    h publish keeps manual RTNE f2bf (bit-identical to passing rounds).
// WAR safety of hbuf slots: unchanged inductive argument (slot t&1 only
// holds tags {t, t-2} while polled for t).

#define B_   64
#define T_   2048
#define D_   256
#define H_   512
#define G4   2048          // 4H
#define TILES 4            // B/16
#define UWP  34            // UWL row length (bf16 elems), 32 + 2 pad
#define BSTR (64 * UWP)    // UWL kk-slab stride in elems

#define OFF_UWL 0
#define SZ_UWL  (24 * 64 * UWP * 2)          // 104448
#define OFF_ZH  (OFF_UWL + SZ_UWL)           // 104448
#define SZ_ZH   (2 * 16 * 512 * 2)           // 32768 (h, double-buffered, swz)
#define OFF_ZX  (OFF_ZH + SZ_ZH)             // 137216
#define SZ_ZX   (2 * 16 * 256 * 2)           // 16384 (x, double-buffered, swz)
#define SMEM_BYTES (OFF_ZX + SZ_ZX)          // 153600 <= 163840

typedef __attribute__((ext_vector_type(8))) short v8s;
typedef __attribute__((ext_vector_type(4))) float v4f;
typedef unsigned long long u64;

__device__ __forceinline__ unsigned short f2bf(float f) {
    unsigned u = __builtin_bit_cast(unsigned, f);
    u = (u + 0x7FFFu + ((u >> 16) & 1u)) >> 16;   // RTNE
    return (unsigned short)u;
}
__device__ __forceinline__ unsigned cvt_pk_bf16(float lo, float hi) {
    unsigned r;
    asm volatile("v_cvt_pk_bf16_f32 %0, %1, %2" : "=v"(r) : "v"(lo), "v"(hi));
    return r;
}
__device__ __forceinline__ u64 pack4(float4 v) {
    unsigned lo = cvt_pk_bf16(v.x, v.y);
    unsigned hi = cvt_pk_bf16(v.z, v.w);
    return (u64)lo | ((u64)hi << 32);
}
__device__ __forceinline__ float fast_tanh(float v) {
    float x = fminf(fmaxf(v, -15.0f), 15.0f);
    float e = __expf(2.0f * x);
    return (e - 1.0f) / (e + 1.0f);
}

__global__ void __launch_bounds__(256, 1)
lstm_persist(const float* __restrict__ x, const float* __restrict__ W,
             const float* __restrict__ U, const float* __restrict__ bias,
             float* __restrict__ out, u64* __restrict__ hbuf /* [2][64][256] */)
{
    extern __shared__ char smem[];
    unsigned short* UWL = (unsigned short*)(smem + OFF_UWL); // [24][64][UWP]
    char*           zhB = smem + OFF_ZH;                     // [2][16][1024B] swz
    char*           zxB = smem + OFF_ZX;                     // [2][16][512B] swz

    const int tid  = threadIdx.x;
    const int g    = blockIdx.x;
    const int tile = g & (TILES - 1);   // batch tile 0..3 (16 batches)
    const int s    = g >> 2;            // h-slice 0..31 (16 h-cols)
    const int l    = tid & 63;
    const int w    = tid >> 6;          // wave 0..3
    const int bn   = l & 15;            // b-col within wave's 16
    const int gi   = bn >> 2;           // gate index of this lane
    const int cc   = bn & 3;            // col within wave's 4 h-cols
    const int q4   = l >> 4;            // C/D row quad & a-frag k-quad
    const bool isG = (gi == 2);
    const bool gi0 = (gi == 0);
    const bool own = ((tid >> 3) == s); // this lane's poll col2 is our slice

    // ---- one-time: stage [U;W] slice (bf16) into LDS ----
    for (int idx = tid; idx < (H_ + D_) * 64; idx += 256) {
        int k = idx >> 6;          // 0..767
        int n = idx & 63;          // local gate col (gate = n>>4, col = n&15)
        int gcol = (n >> 4) * H_ + s * 16 + (n & 15);
        float v = (k < H_) ? U[(size_t)k * G4 + gcol]
                           : W[(size_t)(k - H_) * G4 + gcol];
        UWL[((k >> 5) * 64 + n) * UWP + (k & 31)] = f2bf(v);
    }
    // per-lane bias (register; gate gi, col w*4+cc)
    const float breg = bias[gi * H_ + s * 16 + w * 4 + cc];
    const float oM = isG ? 2.0f : 1.0f;     // activation out = s*oM + oA
    const float oA = isG ? -1.0f : 0.0f;
    const float aM = isG ? 2.0f : 1.0f;     // exp(-aM*v)

    // zero zh[0] for t=0
    for (int n = tid; n < 2048; n += 256)
        *(u64*)(zhB + n * 8) = 0ull;
    // stage x(t=0) -> zx[0] (swizzled)
    #pragma unroll
    for (int p = 0; p < 4; ++p) {
        int n = p * 256 + tid;          // 16 rows x 64 u64
        int row = n >> 6, c4 = n & 63;
        float4 v = *(const float4*)(x + ((size_t)(tile * 16 + row) * T_ + 0) * D_ + c4 * 4);
        *(u64*)(zxB + row * 512 + ((c4 * 8) ^ ((row & 7) << 4))) = pack4(v);
    }
    // preload xr = x[1]
    float4 xr[4];
    #pragma unroll
    for (int p = 0; p < 4; ++p) {
        int n = p * 256 + tid, row = n >> 6, c4 = n & 63;
        xr[p] = *(const float4*)(x + ((size_t)(tile * 16 + row) * T_ + 1) * D_ + c4 * 4);
    }

    // ---- per-lane fragment offsets (XOR-swizzle folded into bases) ----
    const int r    = bn;                 // a-frag row (batch)
    const int krot = (r >> 2) & 1;
    const int qx   = (q4 ^ (r & 3)) << 4;
    const int ahoff0 = r * 1024 + qx + 64 * krot;        // even kk
    const int ahoff1 = r * 1024 + qx + 64 * (krot ^ 1);  // odd kk
    const int axoff0 = r * 512  + qx + 64 * krot;
    const int axoff1 = r * 512  + qx + 64 * (krot ^ 1);
    const unsigned short* brow = UWL + (gi * 16 + w * 4 + cc) * UWP + q4 * 8;
    const int col2o = s * 8 + w * 2 + (cc >> 1);   // own publish col2

    u64 hv[16];
    float creg[4] = {0.0f, 0.0f, 0.0f, 0.0f};
    __syncthreads();

    for (int t = 0; t < T_; ++t) {
        // ---- 1. acc_x = x_t @ Wslice (8 MFMAs, zx[t&1], slabs 16..23) ----
        const char* axb = zxB + (t & 1) * 8192;
        v4f xc0 = {0,0,0,0}, xc1 = {0,0,0,0}, xc2 = {0,0,0,0}, xc3 = {0,0,0,0};
        {
            v8s a0 = *(const v8s*)(axb + axoff0 + 0);
            v8s b0 = *(const v8s*)(brow + (size_t)16 * BSTR);
            xc0 = __builtin_amdgcn_mfma_f32_16x16x32_bf16(a0, b0, xc0, 0, 0, 0);
            v8s a1 = *(const v8s*)(axb + axoff1 + 0);
            v8s b1 = *(const v8s*)(brow + (size_t)17 * BSTR);
            xc1 = __builtin_amdgcn_mfma_f32_16x16x32_bf16(a1, b1, xc1, 0, 0, 0);
            v8s a2 = *(const v8s*)(axb + axoff0 + 128);
            v8s b2 = *(const v8s*)(brow + (size_t)18 * BSTR);
            xc2 = __builtin_amdgcn_mfma_f32_16x16x32_bf16(a2, b2, xc2, 0, 0, 0);
            v8s a3 = *(const v8s*)(axb + axoff1 + 128);
            v8s b3 = *(const v8s*)(brow + (size_t)19 * BSTR);
            xc3 = __builtin_amdgcn_mfma_f32_16x16x32_bf16(a3, b3, xc3, 0, 0, 0);
            v8s a4 = *(const v8s*)(axb + axoff0 + 256);
            v8s b4 = *(const v8s*)(brow + (size_t)20 * BSTR);
            xc0 = __builtin_amdgcn_mfma_f32_16x16x32_bf16(a4, b4, xc0, 0, 0, 0);
            v8s a5 = *(const v8s*)(axb + axoff1 + 256);
            v8s b5 = *(const v8s*)(brow + (size_t)21 * BSTR);
            xc1 = __builtin_amdgcn_mfma_f32_16x16x32_bf16(a5, b5, xc1, 0, 0, 0);
            v8s a6 = *(const v8s*)(axb + axoff0 + 384);
            v8s b6 = *(const v8s*)(brow + (size_t)22 * BSTR);
            xc2 = __builtin_amdgcn_mfma_f32_16x16x32_bf16(a6, b6, xc2, 0, 0, 0);
            v8s a7 = *(const v8s*)(axb + axoff1 + 384);
            v8s b7 = *(const v8s*)(brow + (size_t)23 * BSTR);
            xc3 = __builtin_amdgcn_mfma_f32_16x16x32_bf16(a7, b7, xc3, 0, 0, 0);
        }

        // ---- 2. tag-check / spin (hv loaded last iteration, slot (t-1)&1) --
        if (t > 0) {
            const unsigned tg = (unsigned)(t - 1);
            const u64* hbp = hbuf + (size_t)((t - 1) & 1) * 16384
                                  + (size_t)tile * 4096;
            if (!own) {
                unsigned pend = 0u;
                #pragma unroll
                for (int p = 0; p < 16; ++p)
                    pend |= ((unsigned)((unsigned)hv[p] != tg)) << p;
                while (pend) {
                    #pragma unroll
                    for (int p = 0; p < 16; ++p)
                        if (pend & (1u << p))
                            hv[p] = __hip_atomic_load(hbp + p * 256 + tid,
                                        __ATOMIC_RELAXED, __HIP_MEMORY_SCOPE_AGENT);
                    unsigned np = 0u;
                    #pragma unroll
                    for (int p = 0; p < 16; ++p)
                        np |= ((unsigned)((unsigned)hv[p] != tg)) << p;
                    pend = np;
                }
                // ---- 3. unpack remote h -> zh[t&1] (swizzled dwords) ----
                char* zht = zhB + (t & 1) * 16384;
                #pragma unroll
                for (int p = 0; p < 16; ++p) {
                    *(unsigned*)(zht + p * 1024 + ((tid * 4) ^ ((p & 7) << 4))) =
                        (unsigned)(hv[p] >> 32);
                }
            }
        }

        // ---- 4. stage zx[(t+1)&1] from xr (loaded last iter; retired) ----
        if (t < T_ - 1) {
            char* zxn = zxB + ((t + 1) & 1) * 8192;
            #pragma unroll
            for (int p = 0; p < 4; ++p) {
                int n = p * 256 + tid, row = n >> 6, c4 = n & 63;
                *(u64*)(zxn + row * 512 + ((c4 * 8) ^ ((row & 7) << 4))) = pack4(xr[p]);
            }
            // ---- 5. issue xr = x[t+2] (clamped; consumed next iteration) --
            int tt = (t + 2 < T_) ? t + 2 : T_ - 1;
            #pragma unroll
            for (int p = 0; p < 4; ++p) {
                int n = p * 256 + tid, row = n >> 6, c4 = n & 63;
                xr[p] = *(const float4*)
                    (x + ((size_t)(tile * 16 + row) * T_ + tt) * D_ + c4 * 4);
            }
        }
        __syncthreads();   // (A) zh[t&1], zx ready

        // ---- 6. acc_h = h_{t-1} @ Uslice (16 MFMAs, zh[t&1], slabs 0..15) --
        const char* zht = zhB + (t & 1) * 16384;
        v4f ac0 = {0,0,0,0}, ac1 = {0,0,0,0}, ac2 = {0,0,0,0}, ac3 = {0,0,0,0};
        #pragma unroll
        for (int kk = 0; kk < 16; kk += 4) {
            v8s a0 = *(const v8s*)(zht + ahoff0 + 128 * (kk >> 1));
            v8s b0 = *(const v8s*)(brow + (size_t)(kk + 0) * BSTR);
            ac0 = __builtin_amdgcn_mfma_f32_16x16x32_bf16(a0, b0, ac0, 0, 0, 0);
            v8s a1 = *(const v8s*)(zht + ahoff1 + 128 * (kk >> 1));
            v8s b1 = *(const v8s*)(brow + (size_t)(kk + 1) * BSTR);
            ac1 = __builtin_amdgcn_mfma_f32_16x16x32_bf16(a1, b1, ac1, 0, 0, 0);
            v8s a2 = *(const v8s*)(zht + ahoff0 + 128 * (kk >> 1) + 128);
            v8s b2 = *(const v8s*)(brow + (size_t)(kk + 2) * BSTR);
            ac2 = __builtin_amdgcn_mfma_f32_16x16x32_bf16(a2, b2, ac2, 0, 0, 0);
            v8s a3 = *(const v8s*)(zht + ahoff1 + 128 * (kk >> 1) + 128);
            v8s b3 = *(const v8s*)(brow + (size_t)(kk + 3) * BSTR);
            ac3 = __builtin_amdgcn_mfma_f32_16x16x32_bf16(a3, b3, ac3, 0, 0, 0);
        }

        // ---- 7. epilogue: bias + per-lane activation + in-wave gather ----
        v4f acc = ((ac0 + ac1) + (ac2 + ac3)) + ((xc0 + xc1) + (xc2 + xc3));
        float hval[4], cnl[4];
        #pragma unroll
        for (int rr = 0; rr < 4; ++rr) {
            float v = acc[rr] + breg;
            float e = __expf(-aM * v);
            float sg = 1.0f / (1.0f + e);
            float a  = sg * oM + oA;          // own gate's activation
            // gather the other 3 gates for (rows q4*4+rr, col cc)
            float fA = __shfl_xor(a, 4, 64);
            float gA = __shfl_xor(a, 8, 64);
            float oAv = __shfl_xor(a, 12, 64);
            // valid on gi==0 lanes: a=i, fA=f, gA=g, oAv=o
            float cn = fA * creg[rr] + a * gA;
            creg[rr] = cn;
            cnl[rr] = cn;
            hval[rr] = oAv * fast_tanh(cn);
        }

        if (t == T_ - 1) {
            if (gi0) {
                #pragma unroll
                for (int rr = 0; rr < 4; ++rr) {
                    int grow = tile * 16 + q4 * 4 + rr;
                    int col  = s * 16 + w * 4 + cc;
                    out[(size_t)grow * H_ + col] = hval[rr];
                    out[(size_t)B_ * H_ + (size_t)grow * H_ + col] = cnl[rr];
                }
            }
        } else {
            // ---- 8. issue next hv polls BEFORE publish (slot t&1) ----
            const u64* hbn = hbuf + (size_t)(t & 1) * 16384 + (size_t)tile * 4096;
            if (!own) {
                #pragma unroll
                for (int p = 0; p < 16; ++p)
                    hv[p] = __hip_atomic_load(hbn + p * 256 + tid,
                                __ATOMIC_RELAXED, __HIP_MEMORY_SCOPE_AGENT);
            }
            asm volatile("" ::: "memory");
            // ---- 9. publish h_t (tagged u64) + own-slice local zh write ----
            unsigned hu0 = (unsigned)f2bf(hval[0]);
            unsigned hu1 = (unsigned)f2bf(hval[1]);
            unsigned hu2 = (unsigned)f2bf(hval[2]);
            unsigned hu3 = (unsigned)f2bf(hval[3]);
            unsigned p0 = hu0 | ((unsigned)__shfl_xor((int)hu0, 1, 64) << 16);
            unsigned p1 = hu1 | ((unsigned)__shfl_xor((int)hu1, 1, 64) << 16);
            unsigned p2 = hu2 | ((unsigned)__shfl_xor((int)hu2, 1, 64) << 16);
            unsigned p3 = hu3 | ((unsigned)__shfl_xor((int)hu3, 1, 64) << 16);
            if (gi0 && ((cc & 1) == 0)) {
                u64* hbw = hbuf + (size_t)(t & 1) * 16384;
                char* zhn = zhB + ((t + 1) & 1) * 16384;
                unsigned pr[4] = {p0, p1, p2, p3};
                #pragma unroll
                for (int rr = 0; rr < 4; ++rr) {
                    int row = q4 * 4 + rr;
                    u64 pv = ((u64)pr[rr] << 32) | (u64)(unsigned)t;
                    __hip_atomic_store(hbw + (size_t)(tile * 16 + row) * 256 + col2o,
                                       pv, __ATOMIC_RELAXED, __HIP_MEMORY_SCOPE_AGENT);
                    *(unsigned*)(zhn + row * 1024 +
                                 ((col2o * 4) ^ ((row & 7) << 4))) = pr[rr];
                }
            }
        }
    }
}

extern "C" void kernel_launch(void* const* d_in, const int* in_sizes, int n_in,
                              void* d_out, int out_size, void* d_ws, size_t ws_size,
                              hipStream_t stream) {
    const float* x  = (const float*)d_in[0];   // [64,2048,256]
    const float* W  = (const float*)d_in[1];   // [256,2048]
    const float* U  = (const float*)d_in[2];   // [512,2048]
    const float* bb = (const float*)d_in[3];   // [2048]
    float* out = (float*)d_out;                // [2][64][512] fp32 (h, c)

    u64* hbuf = (u64*)d_ws;                    // tagged u64[2][64][256] = 512KB

    // init tags to 0xFFFFFFFF (never equals any step t) — ws is poisoned 0xAA
    hipMemsetAsync(d_ws, 0xFF, (size_t)2 * 64 * 256 * 8, stream);

    hipFuncSetAttribute((const void*)lstm_persist,
                        hipFuncAttributeMaxDynamicSharedMemorySize, SMEM_BYTES);

    lstm_persist<<<TILES * 32, 256, SMEM_BYTES, stream>>>(
        x, W, U, bb, out, hbuf);
}

// Round 4
// 10937.071 us; speedup vs baseline: 1.7640x; 1.7640x over previous
//
#include <hip/hip_runtime.h>
#include <hip/hip_bf16.h>

// LSTM encoder: B=64, T=2048, D=256, H=512.
// Persistent-RNN: 128 wgs (1/CU), each owns a [768 x 64] bf16 slice of [U;W]
// in LDS. Tagged-u64 dataflow sync (round-2 scheme, best measured 8010us):
// h exchanged as (bf16 h0 | bf16 h1 <<16)<<32 | step_tag u64 words; consumers
// poll the data words until tag == t-1 (polling load IS the data load).
// WAR safety: slot t&1 only ever holds tags {t, t-2} while polled for t.
//
// Round-4 deltas vs round 2 (poll placement, publish mapping, barriers A+B,
// gt epilogue all UNCHANGED from round 2):
//  - zx staging + x-prefetch issue moved BEFORE the tag-check spin: widens
//    the peer-publish -> first-check gap by ~200-300cy of useful work (fewer
//    full repoll rounds) and shortens the post-barrier path.
//  - x prefetch pipelined 2 steps (xr holds x[t+1] staged at t; issue x[t+2]);
//    xr is a full step old when staged -> never waited on.
//  - UWP 40 -> 34 (conflict-lighter b-frag reads, frees 18KB LDS).
//  - x packing via v_cvt_pk_bf16_f32 (2 floats/op).

#define B_   64
#define T_   2048
#define D_   256
#define H_   512
#define G4   2048          // 4H
#define TILES 4            // B/16
#define UWP  34            // UWL row length (bf16 elems), 32 + 2 pad
#define BSTR (64 * UWP)    // UWL kk-slab stride in elems

#define OFF_UWL 0
#define SZ_UWL  (24 * 64 * UWP * 2)          // 104448
#define OFF_ZH  (OFF_UWL + SZ_UWL)           // 104448
#define SZ_ZH   (16 * 512 * 2)               // 16384 (h, single, swizzled)
#define OFF_ZX  (OFF_ZH + SZ_ZH)             // 120832
#define SZ_ZX   (2 * 16 * 256 * 2)           // 16384 (x, double-buffered, swz)
#define OFF_GT  (OFF_ZX + SZ_ZX)             // 137216
#define SZ_GT   (4 * 16 * 17 * 4)            // 4352
#define OFF_BS  (OFF_GT + SZ_GT)             // 141568
#define SZ_BS   (64 * 4)                     // 256
#define SMEM_BYTES (OFF_BS + SZ_BS)          // 141824 <= 163840

typedef __attribute__((ext_vector_type(8))) short v8s;
typedef __attribute__((ext_vector_type(4))) float v4f;
typedef unsigned long long u64;

__device__ __forceinline__ unsigned short f2bf(float f) {
    unsigned u = __builtin_bit_cast(unsigned, f);
    u = (u + 0x7FFFu + ((u >> 16) & 1u)) >> 16;   // RTNE
    return (unsigned short)u;
}
__device__ __forceinline__ unsigned cvt_pk_bf16(float lo, float hi) {
    unsigned r;
    asm volatile("v_cvt_pk_bf16_f32 %0, %1, %2" : "=v"(r) : "v"(lo), "v"(hi));
    return r;
}
__device__ __forceinline__ u64 pack4(float4 v) {
    unsigned lo = cvt_pk_bf16(v.x, v.y);
    unsigned hi = cvt_pk_bf16(v.z, v.w);
    return (u64)lo | ((u64)hi << 32);
}
__device__ __forceinline__ float fast_sigmoid(float v) {
    return 1.0f / (1.0f + __expf(-v));
}
__device__ __forceinline__ float fast_tanh(float v) {
    float x = fminf(fmaxf(v, -15.0f), 15.0f);
    float e = __expf(2.0f * x);
    return (e - 1.0f) / (e + 1.0f);
}

__global__ void __launch_bounds__(256, 1)
lstm_persist(const float* __restrict__ x, const float* __restrict__ W,
             const float* __restrict__ U, const float* __restrict__ bias,
             float* __restrict__ out, u64* __restrict__ hbuf /* [2][64][256] */)
{
    extern __shared__ char smem[];
    unsigned short* UWL = (unsigned short*)(smem + OFF_UWL); // [24][64][UWP]
    char*           zhB = smem + OFF_ZH;                     // [16][1024B] swz
    char*           zxB = smem + OFF_ZX;                     // [2][16][512B] swz
    float*          gt  = (float*)(smem + OFF_GT);           // [4][16][17]
    float*          bs  = (float*)(smem + OFF_BS);           // [64]

    const int tid  = threadIdx.x;
    const int g    = blockIdx.x;
    const int tile = g & (TILES - 1);   // batch tile 0..3 (16 batches)
    const int s    = g >> 2;            // h-slice 0..31 (16 h-cols)
    const int l    = tid & 63;
    const int w    = tid >> 6;          // wave 0..3 == gate index
    const int pb   = tid >> 4;          // pointwise: batch row 0..15
    const int jj   = tid & 15;          // pointwise: h col 0..15

    // ---- one-time: stage [U;W] slice (bf16) + bias into LDS ----
    for (int idx = tid; idx < (H_ + D_) * 64; idx += 256) {
        int k = idx >> 6;          // 0..767
        int n = idx & 63;          // local gate col
        int gcol = (n >> 4) * H_ + s * 16 + (n & 15);
        float v = (k < H_) ? U[(size_t)k * G4 + gcol]
                           : W[(size_t)(k - H_) * G4 + gcol];
        UWL[((k >> 5) * 64 + n) * UWP + (k & 31)] = f2bf(v);
    }
    if (tid < 64) {
        int gcol = (tid >> 4) * H_ + s * 16 + (tid & 15);
        bs[tid] = bias[gcol];
    }
    // zero zh for t=0
    for (int n = tid; n < 2048; n += 256)
        *(u64*)(zhB + n * 8) = 0ull;
    // stage x(t=0) -> zx[0] (swizzled)
    #pragma unroll
    for (int p = 0; p < 4; ++p) {
        int n = p * 256 + tid;          // 16 rows x 64 u64
        int row = n >> 6, c4 = n & 63;
        float4 v = *(const float4*)(x + ((size_t)(tile * 16 + row) * T_ + 0) * D_ + c4 * 4);
        *(u64*)(zxB + row * 512 + ((c4 * 8) ^ ((row & 7) << 4))) = pack4(v);
    }
    // preload xr = x[1]
    float4 xr[4];
    #pragma unroll
    for (int p = 0; p < 4; ++p) {
        int n = p * 256 + tid, row = n >> 6, c4 = n & 63;
        xr[p] = *(const float4*)(x + ((size_t)(tile * 16 + row) * T_ + 1) * D_ + c4 * 4);
    }

    // ---- per-lane fragment offsets (XOR-swizzle folded into bases) ----
    const int r    = l & 15;            // a-frag row
    const int q    = l >> 4;            // a-frag k-quad
    const int krot = (r >> 2) & 1;
    const int qx   = (q ^ (r & 3)) << 4;
    const int ahoff0 = r * 1024 + qx + 64 * krot;        // even kk
    const int ahoff1 = r * 1024 + qx + 64 * (krot ^ 1);  // odd kk
    const int axoff0 = r * 512  + qx + 64 * krot;
    const int axoff1 = r * 512  + qx + 64 * (krot ^ 1);
    const unsigned short* brow = UWL + (w * 16 + r) * UWP + q * 8;

    float creg = 0.0f;       // cell state for (pb, jj) — thread-private
    __syncthreads();

    for (int t = 0; t < T_; ++t) {
        // ---- 1. issue tagged h_{t-1} poll loads (oldest in vmcnt queue) ----
        u64 hv[16];
        u64* hb = hbuf + (size_t)((t - 1) & 1) * 16384 + (size_t)tile * 4096;
        if (t > 0) {
            #pragma unroll
            for (int p = 0; p < 16; ++p)
                hv[p] = __hip_atomic_load(hb + p * 256 + tid,
                                          __ATOMIC_RELAXED, __HIP_MEMORY_SCOPE_AGENT);
        }

        // ---- 2. acc_x = x_t @ Wslice (8 MFMAs, zx[t&1], slabs 16..23) ----
        const char* axb = zxB + (t & 1) * 8192;
        v4f xc0 = {0,0,0,0}, xc1 = {0,0,0,0}, xc2 = {0,0,0,0}, xc3 = {0,0,0,0};
        {
            v8s a0 = *(const v8s*)(axb + axoff0 + 0);
            v8s b0 = *(const v8s*)(brow + (size_t)16 * BSTR);
            xc0 = __builtin_amdgcn_mfma_f32_16x16x32_bf16(a0, b0, xc0, 0, 0, 0);
            v8s a1 = *(const v8s*)(axb + axoff1 + 0);
            v8s b1 = *(const v8s*)(brow + (size_t)17 * BSTR);
            xc1 = __builtin_amdgcn_mfma_f32_16x16x32_bf16(a1, b1, xc1, 0, 0, 0);
            v8s a2 = *(const v8s*)(axb + axoff0 + 128);
            v8s b2 = *(const v8s*)(brow + (size_t)18 * BSTR);
            xc2 = __builtin_amdgcn_mfma_f32_16x16x32_bf16(a2, b2, xc2, 0, 0, 0);
            v8s a3 = *(const v8s*)(axb + axoff1 + 128);
            v8s b3 = *(const v8s*)(brow + (size_t)19 * BSTR);
            xc3 = __builtin_amdgcn_mfma_f32_16x16x32_bf16(a3, b3, xc3, 0, 0, 0);
            v8s a4 = *(const v8s*)(axb + axoff0 + 256);
            v8s b4 = *(const v8s*)(brow + (size_t)20 * BSTR);
            xc0 = __builtin_amdgcn_mfma_f32_16x16x32_bf16(a4, b4, xc0, 0, 0, 0);
            v8s a5 = *(const v8s*)(axb + axoff1 + 256);
            v8s b5 = *(const v8s*)(brow + (size_t)21 * BSTR);
            xc1 = __builtin_amdgcn_mfma_f32_16x16x32_bf16(a5, b5, xc1, 0, 0, 0);
            v8s a6 = *(const v8s*)(axb + axoff0 + 384);
            v8s b6 = *(const v8s*)(brow + (size_t)22 * BSTR);
            xc2 = __builtin_amdgcn_mfma_f32_16x16x32_bf16(a6, b6, xc2, 0, 0, 0);
            v8s a7 = *(const v8s*)(axb + axoff1 + 384);
            v8s b7 = *(const v8s*)(brow + (size_t)23 * BSTR);
            xc3 = __builtin_amdgcn_mfma_f32_16x16x32_bf16(a7, b7, xc3, 0, 0, 0);
        }

        // ---- 3. stage zx[(t+1)&1] from xr (loaded a full step ago) ----
        // Safe pre-barrier: zx[(t+1)&1] was last read at step t-1 phase 2,
        // which all waves finished before barrier A(t-1).
        if (t < T_ - 1) {
            char* zxn = zxB + ((t + 1) & 1) * 8192;
            #pragma unroll
            for (int p = 0; p < 4; ++p) {
                int n = p * 256 + tid, row = n >> 6, c4 = n & 63;
                *(u64*)(zxn + row * 512 + ((c4 * 8) ^ ((row & 7) << 4))) = pack4(xr[p]);
            }
            // ---- 4. issue xr = x[t+2] (clamped; consumed next iteration) --
            int tt = (t + 2 < T_) ? t + 2 : T_ - 1;
            #pragma unroll
            for (int p = 0; p < 4; ++p) {
                int n = p * 256 + tid, row = n >> 6, c4 = n & 63;
                xr[p] = *(const float4*)
                    (x + ((size_t)(tile * 16 + row) * T_ + tt) * D_ + c4 * 4);
            }
        }

        // ---- 5. tag check / re-poll pending; unpack -> zh (swizzled) ----
        if (t > 0) {
            const unsigned tg = (unsigned)(t - 1);
            unsigned pend = 0u;
            #pragma unroll
            for (int p = 0; p < 16; ++p)
                pend |= ((unsigned)hv[p] != tg) ? (1u << p) : 0u;
            while (pend) {
                #pragma unroll
                for (int p = 0; p < 16; ++p)
                    if (pend & (1u << p))
                        hv[p] = __hip_atomic_load(hb + p * 256 + tid,
                                    __ATOMIC_RELAXED, __HIP_MEMORY_SCOPE_AGENT);
                unsigned np = 0u;
                #pragma unroll
                for (int p = 0; p < 16; ++p)
                    np |= ((unsigned)hv[p] != tg) ? (1u << p) : 0u;
                pend = np;
            }
            // zh dword writes: row p, colpair tid; 2-way max (free)
            #pragma unroll
            for (int p = 0; p < 16; ++p) {
                int swz = (p & 7) << 4;
                *(unsigned*)(zhB + p * 1024 + ((tid * 4) ^ swz)) =
                    (unsigned)(hv[p] >> 32);
            }
        }
        __syncthreads();   // (A) zh, zx[(t+1)&1] ready

        // ---- 6. acc_h = h_{t-1} @ Uslice (16 MFMAs, slabs 0..15) ----
        v4f ac0 = {0,0,0,0}, ac1 = {0,0,0,0}, ac2 = {0,0,0,0}, ac3 = {0,0,0,0};
        #pragma unroll
        for (int kk = 0; kk < 16; kk += 4) {
            v8s a0 = *(const v8s*)(zhB + ahoff0 + 128 * (kk >> 1));
            v8s b0 = *(const v8s*)(brow + (size_t)(kk + 0) * BSTR);
            ac0 = __builtin_amdgcn_mfma_f32_16x16x32_bf16(a0, b0, ac0, 0, 0, 0);
            v8s a1 = *(const v8s*)(zhB + ahoff1 + 128 * (kk >> 1));
            v8s b1 = *(const v8s*)(brow + (size_t)(kk + 1) * BSTR);
            ac1 = __builtin_amdgcn_mfma_f32_16x16x32_bf16(a1, b1, ac1, 0, 0, 0);
            v8s a2 = *(const v8s*)(zhB + ahoff0 + 128 * (kk >> 1) + 128);
            v8s b2 = *(const v8s*)(brow + (size_t)(kk + 2) * BSTR);
            ac2 = __builtin_amdgcn_mfma_f32_16x16x32_bf16(a2, b2, ac2, 0, 0, 0);
            v8s a3 = *(const v8s*)(zhB + ahoff1 + 128 * (kk >> 1) + 128);
            v8s b3 = *(const v8s*)(brow + (size_t)(kk + 3) * BSTR);
            ac3 = __builtin_amdgcn_mfma_f32_16x16x32_bf16(a3, b3, ac3, 0, 0, 0);
        }

        // ---- 7. gates + bias + activation -> gt ----
        {
            v4f acc = ((ac0 + ac1) + (ac2 + ac3)) + ((xc0 + xc1) + (xc2 + xc3));
            float bcol = bs[w * 16 + r];
            #pragma unroll
            for (int rr = 0; rr < 4; ++rr) {
                float v = acc[rr] + bcol;
                float a = (w == 2) ? fast_tanh(v) : fast_sigmoid(v);
                gt[(w * 16 + (q * 4 + rr)) * 17 + r] = a;
            }
        }
        __syncthreads();   // (B) gt ready

        // ---- 8. pointwise c,h for (pb, jj); c in register ----
        float iv = gt[(0 * 16 + pb) * 17 + jj];
        float fv = gt[(1 * 16 + pb) * 17 + jj];
        float gv = gt[(2 * 16 + pb) * 17 + jj];
        float ov = gt[(3 * 16 + pb) * 17 + jj];
        float cn = fv * creg + iv * gv;
        creg = cn;
        float h = ov * fast_tanh(cn);

        if (t == T_ - 1) {
            out[(size_t)(tile * 16 + pb) * H_ + s * 16 + jj] = h;
            out[(size_t)B_ * H_ + (size_t)(tile * 16 + pb) * H_ + s * 16 + jj] = cn;
        } else {
            // ---- 9. publish h_t: shfl-pair -> tagged u64, fire-and-forget --
            unsigned hu = (unsigned)f2bf(h);
            unsigned nb = (unsigned)__shfl_xor((int)hu, 1, 64);
            if ((jj & 1) == 0) {
                u64 pv = ((u64)(hu | (nb << 16)) << 32) | (u64)(unsigned)t;
                __hip_atomic_store(hbuf + (size_t)(t & 1) * 16384
                                        + (size_t)(tile * 16 + pb) * 256
                                        + s * 8 + (jj >> 1),
                                   pv, __ATOMIC_RELAXED, __HIP_MEMORY_SCOPE_AGENT);
            }
        }
    }
}

extern "C" void kernel_launch(void* const* d_in, const int* in_sizes, int n_in,
                              void* d_out, int out_size, void* d_ws, size_t ws_size,
                              hipStream_t stream) {
    const float* x  = (const float*)d_in[0];   // [64,2048,256]
    const float* W  = (const float*)d_in[1];   // [256,2048]
    const float* U  = (const float*)d_in[2];   // [512,2048]
    const float* bb = (const float*)d_in[3];   // [2048]
    float* out = (float*)d_out;                // [2][64][512] fp32 (h, c)

    u64* hbuf = (u64*)d_ws;                    // tagged u64[2][64][256] = 512KB

    // init tags to 0xFFFFFFFF (never equals any step t) — ws is poisoned 0xAA
    hipMemsetAsync(d_ws, 0xFF, (size_t)2 * 64 * 256 * 8, stream);

    hipFuncSetAttribute((const void*)lstm_persist,
                        hipFuncAttributeMaxDynamicSharedMemorySize, SMEM_BYTES);

    lstm_persist<<<TILES * 32, 256, SMEM_BYTES, stream>>>(
        x, W, U, bb, out, hbuf);
}

// Round 5
// 7396.380 us; speedup vs baseline: 2.6085x; 1.4787x over previous
//
#include <hip/hip_runtime.h>
#include <hip/hip_bf16.h>

// LSTM encoder: B=64, T=2048, D=256, H=512.
// Persistent-RNN: 128 wgs (1/CU via ~156KB LDS), each owns a [768 x 64] bf16
// slice of [U;W] in LDS.
//
// Tagged-u64 dataflow sync (round-2 scheme, verified 8010us): h exchanged as
// (bf16 h0 | bf16 h1 <<16)<<32 | step_tag u64 words; consumers poll the data
// words until tag == t-1 (the polling load IS the data load). WAR safety:
// slot t&1 only ever holds tags {t, t-2} while polled for t, inductively.
//
// ROUND-5 SINGLE DELTA vs round 2: the x_{t+1} prefetch (xr) is issued AFTER
// the spin loop instead of before it. Mechanism: repoll rounds read their own
// just-issued loads -> in-order vmcnt forces vmcnt(0), which previously also
// drained the 4 in-flight x loads (L3/HBM latency injected into every spin
// round). With xr issued post-spin, spin rounds drain only poll loads; xr is
// consumed at stage-zx, behind barrier A + 16 MFMAs (~800cy of cover).
// Everything else (poll placement, publish mapping, UWP=40, barriers A+B,
// gt epilogue, manual-RTNE packing) is byte-identical to round 2.

#define B_   64
#define T_   2048
#define D_   256
#define H_   512
#define G4   2048          // 4H
#define KK   24            // (H+D)/32
#define TILES 4            // B/16
#define UWP  40            // UWL row length (bf16 elems), 32 + 8 pad
#define BSTR (64 * UWP)    // UWL kk-slab stride in elems

#define OFF_UWL 0
#define SZ_UWL  (KK * 64 * UWP * 2)          // 122880
#define OFF_ZH  (OFF_UWL + SZ_UWL)           // 122880
#define SZ_ZH   (16 * 512 * 2)               // 16384 (h, XOR-swizzled)
#define OFF_ZX  (OFF_ZH + SZ_ZH)             // 139264
#define SZ_ZX   (2 * 16 * 256 * 2)           // 16384 (x, double-buffered, swz)
#define OFF_GT  (OFF_ZX + SZ_ZX)             // 155648
#define SZ_GT   (4 * 16 * 17 * 4)            // 4352
#define OFF_BS  (OFF_GT + SZ_GT)             // 160000
#define SZ_BS   (64 * 4)                     // 256
#define SMEM_BYTES (OFF_BS + SZ_BS)          // 160256 <= 163840

typedef __attribute__((ext_vector_type(8))) short v8s;
typedef __attribute__((ext_vector_type(4))) float v4f;
typedef unsigned long long u64;

__device__ __forceinline__ unsigned short f2bf(float f) {
    unsigned u = __builtin_bit_cast(unsigned, f);
    u = (u + 0x7FFFu + ((u >> 16) & 1u)) >> 16;   // RTNE
    return (unsigned short)u;
}
__device__ __forceinline__ u64 pack4(float4 v) {
    return (u64)((unsigned)f2bf(v.x) | ((unsigned)f2bf(v.y) << 16)) |
           ((u64)((unsigned)f2bf(v.z) | ((unsigned)f2bf(v.w) << 16)) << 32);
}
__device__ __forceinline__ float fast_sigmoid(float v) {
    return 1.0f / (1.0f + __expf(-v));
}
__device__ __forceinline__ float fast_tanh(float v) {
    float x = fminf(fmaxf(v, -15.0f), 15.0f);
    float e = __expf(2.0f * x);
    return (e - 1.0f) / (e + 1.0f);
}

__global__ void __launch_bounds__(256, 1)
lstm_persist(const float* __restrict__ x, const float* __restrict__ W,
             const float* __restrict__ U, const float* __restrict__ bias,
             float* __restrict__ out, u64* __restrict__ hbuf /* [2][64][256] */)
{
    extern __shared__ char smem[];
    unsigned short* UWL = (unsigned short*)(smem + OFF_UWL); // [KK][64][UWP]
    char*           zhB = smem + OFF_ZH;                     // [16][1024B] swz
    char*           zxB = smem + OFF_ZX;                     // [2][16][512B] swz
    float*          gt  = (float*)(smem + OFF_GT);           // [4][16][17]
    float*          bs  = (float*)(smem + OFF_BS);           // [64]

    const int tid  = threadIdx.x;
    const int g    = blockIdx.x;
    const int tile = g & (TILES - 1);   // batch tile 0..3 (16 batches)
    const int s    = g >> 2;            // h-slice 0..31 (16 h-cols)
    const int l    = tid & 63;
    const int w    = tid >> 6;          // wave 0..3 == gate index
    const int pb   = tid >> 4;          // pointwise: batch row 0..15
    const int jj   = tid & 15;          // pointwise: h col 0..15

    // ---- one-time: stage [U;W] slice (bf16) + bias into LDS ----
    for (int idx = tid; idx < (H_ + D_) * 64; idx += 256) {
        int k = idx >> 6;          // 0..767
        int n = idx & 63;          // local gate col
        int gcol = (n >> 4) * H_ + s * 16 + (n & 15);
        float v = (k < H_) ? U[(size_t)k * G4 + gcol]
                           : W[(size_t)(k - H_) * G4 + gcol];
        UWL[((k >> 5) * 64 + n) * UWP + (k & 31)] = f2bf(v);
    }
    if (tid < 64) {
        int gcol = (tid >> 4) * H_ + s * 16 + (tid & 15);
        bs[tid] = bias[gcol];
    }
    // zero zh for t=0
    for (int n = tid; n < 2048; n += 256)
        *(u64*)(zhB + n * 8) = 0ull;
    // stage x(t=0) -> zx[0] (swizzled)
    #pragma unroll
    for (int p = 0; p < 4; ++p) {
        int n = p * 256 + tid;          // 16 rows x 64 u64
        int row = n >> 6, c4 = n & 63;
        float4 v = *(const float4*)(x + ((size_t)(tile * 16 + row) * T_ + 0) * D_ + c4 * 4);
        *(u64*)(zxB + row * 512 + ((c4 * 8) ^ ((row & 7) << 4))) = pack4(v);
    }

    // ---- per-lane fragment offsets (XOR-swizzle folded into bases) ----
    const int r    = l & 15;            // a-frag row
    const int q    = l >> 4;            // a-frag k-quad
    const int krot = (r >> 2) & 1;
    const int qx   = (q ^ (r & 3)) << 4;
    const int ahoff0 = r * 1024 + qx + 64 * krot;        // even kk
    const int ahoff1 = r * 1024 + qx + 64 * (krot ^ 1);  // odd kk
    const int axoff0 = r * 512  + qx + 64 * krot;
    const int axoff1 = r * 512  + qx + 64 * (krot ^ 1);
    const unsigned short* brow = UWL + (w * 16 + r) * UWP + q * 8;

    float creg = 0.0f;       // cell state for (pb, jj) — thread-private
    __syncthreads();

    for (int t = 0; t < T_; ++t) {
        // ---- 1. issue tagged h_{t-1} poll loads ----
        u64 hv[16];
        u64* hb = hbuf + (size_t)((t - 1) & 1) * 16384 + (size_t)tile * 4096;
        if (t > 0) {
            #pragma unroll
            for (int p = 0; p < 16; ++p)
                hv[p] = __hip_atomic_load(hb + p * 256 + tid,
                                          __ATOMIC_RELAXED, __HIP_MEMORY_SCOPE_AGENT);
        }

        // ---- 2. acc_x = x_t @ Wslice (8 MFMAs, zx[t&1]; fills poll window) --
        const char* axb = zxB + (t & 1) * 8192;
        v4f xc0 = {0,0,0,0}, xc1 = {0,0,0,0}, xc2 = {0,0,0,0}, xc3 = {0,0,0,0};
        {
            v8s a0 = *(const v8s*)(axb + axoff0 + 0);
            v8s b0 = *(const v8s*)(brow + (size_t)16 * BSTR);
            xc0 = __builtin_amdgcn_mfma_f32_16x16x32_bf16(a0, b0, xc0, 0, 0, 0);
            v8s a1 = *(const v8s*)(axb + axoff1 + 0);
            v8s b1 = *(const v8s*)(brow + (size_t)17 * BSTR);
            xc1 = __builtin_amdgcn_mfma_f32_16x16x32_bf16(a1, b1, xc1, 0, 0, 0);
            v8s a2 = *(const v8s*)(axb + axoff0 + 128);
            v8s b2 = *(const v8s*)(brow + (size_t)18 * BSTR);
            xc2 = __builtin_amdgcn_mfma_f32_16x16x32_bf16(a2, b2, xc2, 0, 0, 0);
            v8s a3 = *(const v8s*)(axb + axoff1 + 128);
            v8s b3 = *(const v8s*)(brow + (size_t)19 * BSTR);
            xc3 = __builtin_amdgcn_mfma_f32_16x16x32_bf16(a3, b3, xc3, 0, 0, 0);
            v8s a4 = *(const v8s*)(axb + axoff0 + 256);
            v8s b4 = *(const v8s*)(brow + (size_t)20 * BSTR);
            xc0 = __builtin_amdgcn_mfma_f32_16x16x32_bf16(a4, b4, xc0, 0, 0, 0);
            v8s a5 = *(const v8s*)(axb + axoff1 + 256);
            v8s b5 = *(const v8s*)(brow + (size_t)21 * BSTR);
            xc1 = __builtin_amdgcn_mfma_f32_16x16x32_bf16(a5, b5, xc1, 0, 0, 0);
            v8s a6 = *(const v8s*)(axb + axoff0 + 384);
            v8s b6 = *(const v8s*)(brow + (size_t)22 * BSTR);
            xc2 = __builtin_amdgcn_mfma_f32_16x16x32_bf16(a6, b6, xc2, 0, 0, 0);
            v8s a7 = *(const v8s*)(axb + axoff1 + 384);
            v8s b7 = *(const v8s*)(brow + (size_t)23 * BSTR);
            xc3 = __builtin_amdgcn_mfma_f32_16x16x32_bf16(a7, b7, xc3, 0, 0, 0);
        }

        // ---- 3. tag check / re-poll pending; unpack -> zh (swizzled) ----
        // (no other vmem in flight below the polls -> repoll drains polls only)
        if (t > 0) {
            const unsigned tg = (unsigned)(t - 1);
            unsigned pend = 0u;
            #pragma unroll
            for (int p = 0; p < 16; ++p)
                pend |= ((unsigned)hv[p] != tg) ? (1u << p) : 0u;
            while (pend) {
                #pragma unroll
                for (int p = 0; p < 16; ++p)
                    if (pend & (1u << p))
                        hv[p] = __hip_atomic_load(hb + p * 256 + tid,
                                    __ATOMIC_RELAXED, __HIP_MEMORY_SCOPE_AGENT);
                unsigned np = 0u;
                #pragma unroll
                for (int p = 0; p < 16; ++p)
                    np |= ((unsigned)hv[p] != tg) ? (1u << p) : 0u;
                pend = np;
            }
            // zh dword writes: row p, colpair tid; 2-way max (free)
            #pragma unroll
            for (int p = 0; p < 16; ++p) {
                int swz = (p & 7) << 4;
                *(unsigned*)(zhB + p * 1024 + ((tid * 4) ^ swz)) =
                    (unsigned)(hv[p] >> 32);
            }
        }

        // ---- 4. issue x_{t+1} loads (post-spin: never drained by repolls;
        //         consumed at stage-zx behind barrier A + acc_h) ----
        float4 xr[4];
        if (t < T_ - 1) {
            #pragma unroll
            for (int p = 0; p < 4; ++p) {
                int n = p * 256 + tid, row = n >> 6, c4 = n & 63;
                xr[p] = *(const float4*)
                    (x + ((size_t)(tile * 16 + row) * T_ + (t + 1)) * D_ + c4 * 4);
            }
        }
        __syncthreads();   // (A) zh ready

        // ---- 5. acc_h = h_{t-1} @ Uslice (16 MFMAs, slabs 0..15) ----
        v4f ac0 = {0,0,0,0}, ac1 = {0,0,0,0}, ac2 = {0,0,0,0}, ac3 = {0,0,0,0};
        #pragma unroll
        for (int kk = 0; kk < 16; kk += 4) {
            v8s a0 = *(const v8s*)(zhB + ahoff0 + 128 * (kk >> 1));
            v8s b0 = *(const v8s*)(brow + (size_t)(kk + 0) * BSTR);
            ac0 = __builtin_amdgcn_mfma_f32_16x16x32_bf16(a0, b0, ac0, 0, 0, 0);
            v8s a1 = *(const v8s*)(zhB + ahoff1 + 128 * (kk >> 1));
            v8s b1 = *(const v8s*)(brow + (size_t)(kk + 1) * BSTR);
            ac1 = __builtin_amdgcn_mfma_f32_16x16x32_bf16(a1, b1, ac1, 0, 0, 0);
            v8s a2 = *(const v8s*)(zhB + ahoff0 + 128 * (kk >> 1) + 128);
            v8s b2 = *(const v8s*)(brow + (size_t)(kk + 2) * BSTR);
            ac2 = __builtin_amdgcn_mfma_f32_16x16x32_bf16(a2, b2, ac2, 0, 0, 0);
            v8s a3 = *(const v8s*)(zhB + ahoff1 + 128 * (kk >> 1) + 128);
            v8s b3 = *(const v8s*)(brow + (size_t)(kk + 3) * BSTR);
            ac3 = __builtin_amdgcn_mfma_f32_16x16x32_bf16(a3, b3, ac3, 0, 0, 0);
        }

        // ---- 6. stage x_{t+1} -> zx[(t+1)&1] (xr latency covered by 5) ----
        if (t < T_ - 1) {
            char* zxn = zxB + ((t + 1) & 1) * 8192;
            #pragma unroll
            for (int p = 0; p < 4; ++p) {
                int n = p * 256 + tid, row = n >> 6, c4 = n & 63;
                *(u64*)(zxn + row * 512 + ((c4 * 8) ^ ((row & 7) << 4))) = pack4(xr[p]);
            }
        }

        // ---- 7. gates + bias + activation -> gt ----
        {
            v4f acc = ((ac0 + ac1) + (ac2 + ac3)) + ((xc0 + xc1) + (xc2 + xc3));
            float bcol = bs[w * 16 + r];
            #pragma unroll
            for (int rr = 0; rr < 4; ++rr) {
                float v = acc[rr] + bcol;
                float a = (w == 2) ? fast_tanh(v) : fast_sigmoid(v);
                gt[(w * 16 + (q * 4 + rr)) * 17 + r] = a;
            }
        }
        __syncthreads();   // (B) gt ready

        // ---- 8. pointwise c,h for (pb, jj); c in register ----
        float iv = gt[(0 * 16 + pb) * 17 + jj];
        float fv = gt[(1 * 16 + pb) * 17 + jj];
        float gv = gt[(2 * 16 + pb) * 17 + jj];
        float ov = gt[(3 * 16 + pb) * 17 + jj];
        float cn = fv * creg + iv * gv;
        creg = cn;
        float h = ov * fast_tanh(cn);

        if (t == T_ - 1) {
            out[(size_t)(tile * 16 + pb) * H_ + s * 16 + jj] = h;
            out[(size_t)B_ * H_ + (size_t)(tile * 16 + pb) * H_ + s * 16 + jj] = cn;
        } else {
            // ---- 9. publish h_t: shfl-pair -> tagged u64, fire-and-forget --
            unsigned hu = (unsigned)f2bf(h);
            unsigned nb = (unsigned)__shfl_xor((int)hu, 1, 64);
            if ((jj & 1) == 0) {
                u64 pv = ((u64)(hu | (nb << 16)) << 32) | (u64)(unsigned)t;
                __hip_atomic_store(hbuf + (size_t)(t & 1) * 16384
                                        + (size_t)(tile * 16 + pb) * 256
                                        + s * 8 + (jj >> 1),
                                   pv, __ATOMIC_RELAXED, __HIP_MEMORY_SCOPE_AGENT);
            }
        }
    }
}

extern "C" void kernel_launch(void* const* d_in, const int* in_sizes, int n_in,
                              void* d_out, int out_size, void* d_ws, size_t ws_size,
                              hipStream_t stream) {
    const float* x  = (const float*)d_in[0];   // [64,2048,256]
    const float* W  = (const float*)d_in[1];   // [256,2048]
    const float* U  = (const float*)d_in[2];   // [512,2048]
    const float* bb = (const float*)d_in[3];   // [2048]
    float* out = (float*)d_out;                // [2][64][512] fp32 (h, c)

    u64* hbuf = (u64*)d_ws;                    // tagged u64[2][64][256] = 512KB

    // init tags to 0xFFFFFFFF (never equals any step t) — ws is poisoned 0xAA
    hipMemsetAsync(d_ws, 0xFF, (size_t)2 * 64 * 256 * 8, stream);

    hipFuncSetAttribute((const void*)lstm_persist,
                        hipFuncAttributeMaxDynamicSharedMemorySize, SMEM_BYTES);

    lstm_persist<<<TILES * 32, 256, SMEM_BYTES, stream>>>(
        x, W, U, bb, out, hbuf);
}